// Round 1
// baseline (80.563 us; speedup 1.0000x reference)
//
#include <hip/hip_runtime.h>

#define NHEADS 16
#define HDIM   64
#define NFEAT  32
#define PDIM   16
#define NQUAD  2
#define GB     8      // b's processed per wave (omega/anchor reg amortization)
#define WAVES_PB 4    // waves per 256-thread block

// out[b, r, h, p, m] flat = b*16384 + r*8192 + h*512 + p*32 + m
__global__ __launch_bounds__(256, 3)
void slay_kernel(const float* __restrict__ x,
                 const float* __restrict__ omega,
                 const float* __restrict__ anchors,
                 const float* __restrict__ qn,
                 const float* __restrict__ qw,
                 float* __restrict__ out)
{
    __shared__ __align__(16) float s_prf[WAVES_PB][64];   // [r*32+m]
    __shared__ __align__(16) float s_poly[WAVES_PB][16];  // [p]

    const int tid  = threadIdx.x;
    const int wv   = tid >> 6;
    const int lane = tid & 63;
    const int h    = blockIdx.x & 15;
    const int b0   = ((blockIdx.x >> 4) * WAVES_PB + wv) * GB;

    const int r = lane >> 5;   // quadrature node index for this lane
    const int m = lane & 31;   // feature index for this lane
    const int p = lane & 15;   // poly index (4x redundant across lanes)

    // per-lane quadrature constants
    const float sR     = fmaxf(qn[r], 1e-6f);
    const float sq2s   = sqrtf(2.0f * sR);
    const float scaleR = sqrtf(fmaxf(qw[r], 1e-6f)) / sqrtf(32.0f + 1e-6f);

    // preload omega column om[d] = omega[r][h][d][m]  (coalesced: 2x128B per d)
    float om[64];
    {
        const float* oc = omega + ((size_t)(r * NHEADS + h) * HDIM) * NFEAT + m;
        #pragma unroll
        for (int d = 0; d < 64; ++d) om[d] = oc[(size_t)d * NFEAT];
    }
    // preload anchors row an[d] = anchors[p][d] (16 unique addrs, L1-resident)
    float an[64];
    {
        const float* ac = anchors + p * HDIM;
        #pragma unroll
        for (int d = 0; d < 64; ++d) an[d] = ac[d];
    }

    for (int bb = 0; bb < GB; ++bb) {
        const int b = b0 + bb;

        // ---- load + normalize x[b, h, :] (lane = d) ----
        const float xv = x[(size_t)b * (NHEADS * HDIM) + h * HDIM + lane];
        float ss = xv * xv;
        #pragma unroll
        for (int off = 32; off > 0; off >>= 1) ss += __shfl_xor(ss, off, 64);
        const float xn = xv / fmaxf(sqrtf(ss), 1e-4f);

        // ---- dot products: readlane broadcast (VALU pipe, no LDS traffic) ----
        float accR = 0.f, accP = 0.f;
        #pragma unroll
        for (int d = 0; d < 64; ++d) {
            const float sx = __uint_as_float(
                __builtin_amdgcn_readlane(__float_as_uint(xn), d));
            accR = fmaf(sx, om[d], accR);
            accP = fmaf(sx, an[d], accP);
        }

        // ---- feature epilogues ----
        const float arg  = fminf(fmaxf(accR * sq2s - sR, -20.f), 20.f);
        const float prf  = expf(arg) * scaleR;
        const float pc   = fminf(fmaxf(accP, -1.f), 1.f);
        const float poly = pc * pc * 0.25f;

        // ---- stage per-wave, then expand + write ----
        __syncthreads();
        s_prf[wv][lane] = prf;
        if (lane < 16) s_poly[wv][lane] = poly;
        __syncthreads();

        float* ob = out + (size_t)b * (NQUAD * NHEADS * PDIM * NFEAT)
                        + (size_t)h * (PDIM * NFEAT);
        #pragma unroll
        for (int i = 0; i < 4; ++i) {
            const int rr = i >> 1;
            const int pp = (i * 8 + (lane >> 3)) & 15;
            const float  pf = s_poly[wv][pp];
            const float4 pr = *(const float4*)&s_prf[wv][rr * 32 + (lane & 7) * 4];
            float4 v;
            v.x = pf * pr.x; v.y = pf * pr.y; v.z = pf * pr.z; v.w = pf * pr.w;
            *(float4*)(ob + (size_t)rr * (NHEADS * PDIM * NFEAT)
                          + (i & 1) * 256 + lane * 4) = v;
        }
    }
}

extern "C" void kernel_launch(void* const* d_in, const int* in_sizes, int n_in,
                              void* d_out, int out_size, void* d_ws, size_t ws_size,
                              hipStream_t stream)
{
    const float* x       = (const float*)d_in[0];
    const float* omega   = (const float*)d_in[1];
    const float* anchors = (const float*)d_in[2];
    const float* qn      = (const float*)d_in[3];
    const float* qw      = (const float*)d_in[4];
    float* out = (float*)d_out;

    const int Bsz = in_sizes[0] / (NHEADS * HDIM);          // 4096
    dim3 grid((Bsz / (WAVES_PB * GB)) * NHEADS);            // 128 * 16 = 2048
    slay_kernel<<<grid, 256, 0, stream>>>(x, omega, anchors, qn, qw, out);
}

// Round 2
// 62.364 us; speedup vs baseline: 1.2918x; 1.2918x over previous
//
#include <hip/hip_runtime.h>

#define NHEADS 16
#define HDIM   64
#define NFEAT  32
#define PDIM   16
#define NQUAD  2
#define GB     8      // b's processed per wave
#define WAVES_PB 4    // waves per 256-thread block

// out[b, r, h, p, m] flat = b*16384 + r*8192 + h*512 + p*32 + m
__global__ __launch_bounds__(256, 4)
void slay_kernel(const float* __restrict__ x,
                 const float* __restrict__ omega,
                 const float* __restrict__ anchors,
                 const float* __restrict__ qn,
                 const float* __restrict__ qw,
                 float* __restrict__ out)
{
    // all buffers are PER-WAVE: no __syncthreads needed, wave_barrier only
    __shared__ __align__(16) float s_xn [WAVES_PB][64];
    __shared__ __align__(16) float s_prf[WAVES_PB][64];
    __shared__ __align__(16) float s_poly[WAVES_PB][16];

    const int tid  = threadIdx.x;
    const int wv   = tid >> 6;
    const int lane = tid & 63;
    const int h    = blockIdx.x & 15;
    const int b0   = ((blockIdx.x >> 4) * WAVES_PB + wv) * GB;

    const int r = lane >> 5;   // quadrature node index
    const int m = lane & 31;   // feature index
    const int p = lane & 15;   // poly index (4x redundant)
    const int g = lane >> 4;   // d-group for poly partial dot

    const float sR     = fmaxf(qn[r], 1e-6f);
    const float sq2s   = sqrtf(2.0f * sR);
    const float scaleR = sqrtf(fmaxf(qw[r], 1e-6f)) / sqrtf(32.0f + 1e-6f);

    // preload omega column om[d] = omega[r][h][d][m]
    float om[64];
    {
        const float* oc = omega + ((size_t)(r * NHEADS + h) * HDIM) * NFEAT + m;
        #pragma unroll
        for (int d = 0; d < 64; ++d) om[d] = oc[(size_t)d * NFEAT];
    }
    // anchors slice: an[dd] = anchors[p][g*16 + dd]  (only 16 regs)
    float an[16];
    {
        const float* ac = anchors + p * HDIM + g * 16;
        #pragma unroll
        for (int dd = 0; dd < 16; ++dd) an[dd] = ac[dd];
    }

    // hoist all GB x loads (independent; overlap their latency)
    float xvv[GB];
    {
        const float* xb = x + (size_t)b0 * (NHEADS * HDIM) + h * HDIM + lane;
        #pragma unroll
        for (int bb = 0; bb < GB; ++bb) xvv[bb] = xb[(size_t)bb * (NHEADS * HDIM)];
    }

    #pragma unroll
    for (int bb = 0; bb < GB; ++bb) {
        const int b = b0 + bb;

        // ---- normalize x[b, h, :] (lane = d) ----
        float ss = xvv[bb] * xvv[bb];
        #pragma unroll
        for (int off = 32; off > 0; off >>= 1) ss += __shfl_xor(ss, off, 64);
        const float xn = xvv[bb] / fmaxf(sqrtf(ss), 1e-4f);

        // stage xn per-wave for the poly path (WAR fence, then write)
        __builtin_amdgcn_wave_barrier();
        s_xn[wv][lane] = xn;
        __builtin_amdgcn_wave_barrier();

        // ---- prf dot: readlane broadcast, 4 independent accum chains ----
        float a0 = 0.f, a1 = 0.f, a2 = 0.f, a3 = 0.f;
        #pragma unroll
        for (int d = 0; d < 64; d += 4) {
            const float s0 = __uint_as_float(__builtin_amdgcn_readlane(__float_as_uint(xn), d + 0));
            const float s1 = __uint_as_float(__builtin_amdgcn_readlane(__float_as_uint(xn), d + 1));
            const float s2 = __uint_as_float(__builtin_amdgcn_readlane(__float_as_uint(xn), d + 2));
            const float s3 = __uint_as_float(__builtin_amdgcn_readlane(__float_as_uint(xn), d + 3));
            a0 = fmaf(s0, om[d + 0], a0);
            a1 = fmaf(s1, om[d + 1], a1);
            a2 = fmaf(s2, om[d + 2], a2);
            a3 = fmaf(s3, om[d + 3], a3);
        }
        const float accR = (a0 + a1) + (a2 + a3);

        // ---- poly dot: this lane's 16-d slice from LDS, group-reduce ----
        float p0 = 0.f, p1 = 0.f, p2 = 0.f, p3 = 0.f;
        #pragma unroll
        for (int q4 = 0; q4 < 4; ++q4) {
            const float4 xq = *(const float4*)&s_xn[wv][g * 16 + q4 * 4];
            p0 = fmaf(xq.x, an[q4 * 4 + 0], p0);
            p1 = fmaf(xq.y, an[q4 * 4 + 1], p1);
            p2 = fmaf(xq.z, an[q4 * 4 + 2], p2);
            p3 = fmaf(xq.w, an[q4 * 4 + 3], p3);
        }
        float accP = (p0 + p1) + (p2 + p3);
        accP += __shfl_xor(accP, 16, 64);   // combine the 4 d-groups
        accP += __shfl_xor(accP, 32, 64);

        // ---- feature epilogues ----
        const float arg  = fminf(fmaxf(accR * sq2s - sR, -20.f), 20.f);
        const float prf  = expf(arg) * scaleR;
        const float pc   = fminf(fmaxf(accP, -1.f), 1.f);
        const float poly = pc * pc * 0.25f;

        // ---- stage per-wave, expand + write (no block barrier!) ----
        __builtin_amdgcn_wave_barrier();
        s_prf[wv][lane] = prf;
        if (lane < 16) s_poly[wv][lane] = poly;
        __builtin_amdgcn_wave_barrier();

        float* ob = out + (size_t)b * (NQUAD * NHEADS * PDIM * NFEAT)
                        + (size_t)h * (PDIM * NFEAT);
        #pragma unroll
        for (int i = 0; i < 4; ++i) {
            const int rr = i >> 1;
            const int pp = (i * 8 + (lane >> 3)) & 15;
            const float  pf = s_poly[wv][pp];
            const float4 pr = *(const float4*)&s_prf[wv][rr * 32 + (lane & 7) * 4];
            float4 v;
            v.x = pf * pr.x; v.y = pf * pr.y; v.z = pf * pr.z; v.w = pf * pr.w;
            *(float4*)(ob + (size_t)rr * (NHEADS * PDIM * NFEAT)
                          + (i & 1) * 256 + lane * 4) = v;
        }
    }
}

extern "C" void kernel_launch(void* const* d_in, const int* in_sizes, int n_in,
                              void* d_out, int out_size, void* d_ws, size_t ws_size,
                              hipStream_t stream)
{
    const float* x       = (const float*)d_in[0];
    const float* omega   = (const float*)d_in[1];
    const float* anchors = (const float*)d_in[2];
    const float* qn      = (const float*)d_in[3];
    const float* qw      = (const float*)d_in[4];
    float* out = (float*)d_out;

    const int Bsz = in_sizes[0] / (NHEADS * HDIM);          // 4096
    dim3 grid((Bsz / (WAVES_PB * GB)) * NHEADS);            // 128 * 16 = 2048
    slay_kernel<<<grid, 256, 0, stream>>>(x, omega, anchors, qn, qw, out);
}